// Round 6
// baseline (83.392 us; speedup 1.0000x reference)
//
#include <hip/hip_runtime.h>

// UpFilter2d: 2x zero-injection upsample + depthwise 5x5 Pascal filter, fused.
// Parity + separability: kernel = outer([1,4,6,4,1])/256. Even output
// rows/cols: taps [1,6,1]; odd: [4,4] (scales folded: 1/256, 4/256, 16/256).
//
// R5 layout: wave = RR=4 consecutive input rows of one (b,c) image.
//   - Loads RR+2=6 dense 512B float2 rows (1.5x redundancy vs 3x in R4).
//   - Vertical pass in registers (rows reused across the 4 output pairs),
//     column halos via shfl (lane 0/63 edges == image edges -> zero pad).
//   - Stores 8 dense 1KiB output rows (8KiB contiguous per wave).
//   - Bijective XCD-chunk swizzle: 8192 blocks -> 1024 contiguous per XCD,
//     so halo rows shared between neighbor row-groups hit the same L2.

#define BB 8
#define CC 128
#define HH 128
#define WW 128
#define RR 4   // input rows per wave

typedef float f32x2 __attribute__((ext_vector_type(2)));
typedef float f32x4 __attribute__((ext_vector_type(4)));

__global__ __launch_bounds__(256) void upfilter2d_kernel(
    const float* __restrict__ x,
    float* __restrict__ out)
{
    // XCD-chunked bijective swizzle (grid = 8192, 8 XCDs, 1024 blocks each)
    int bid = blockIdx.x;
    int swz = (bid & 7) * ((BB * CC * (HH / RR) * 64 / 256) >> 3) + (bid >> 3);
    int tid = swz * 256 + (int)threadIdx.x;

    int lane = tid & 63;
    int w    = tid >> 6;
    int rg   = w & (HH / RR - 1);   // row-group 0..31
    int bc   = w >> 5;              // 0..1023 (B*C)
    int y0   = rg * RR;

    const float* xp = x + (size_t)bc * (HH * WW) + 2 * lane;

    // rows y0-1 .. y0+RR, dense float2 per row (wave covers full 512B row)
    f32x2 v[RR + 2];
    f32x2 z = {0.f, 0.f};
    v[0] = (rg > 0) ? *reinterpret_cast<const f32x2*>(xp + (y0 - 1) * WW) : z;
#pragma unroll
    for (int r = 1; r <= RR; ++r)
        v[r] = *reinterpret_cast<const f32x2*>(xp + (y0 + r - 1) * WW);
    v[RR + 1] = (rg < HH / RR - 1)
        ? *reinterpret_cast<const f32x2*>(xp + (y0 + RR) * WW) : z;

    const int OW = 2 * WW;  // 256
    float* op = out + (size_t)bc * (2 * HH * OW) + (size_t)(2 * y0) * OW + 4 * lane;

#pragma unroll
    for (int r = 0; r < RR; ++r) {
        // vertical: even-row taps [1,6,1] on rows y-1,y,y+1; odd taps [4,4]
        float tE0 = (v[r].x + v[r + 2].x) + 6.f * v[r + 1].x;
        float tE1 = (v[r].y + v[r + 2].y) + 6.f * v[r + 1].y;
        float tO0 = v[r + 1].x + v[r + 2].x;
        float tO1 = v[r + 1].y + v[r + 2].y;

        // column halos from neighbor lanes (image edge == lane-group edge)
        float tEm = __shfl_up(tE1, 1);   if (lane == 0)  tEm = 0.f;
        float tOm = __shfl_up(tO1, 1);   if (lane == 0)  tOm = 0.f;
        float tEp = __shfl_down(tE0, 1); if (lane == 63) tEp = 0.f;
        float tOp = __shfl_down(tO0, 1); if (lane == 63) tOp = 0.f;

        // horizontal: out cols 4l..4l+3
        f32x4 oE, oO;
        oE.x = ((tEm + tE1) + 6.f * tE0) * 0.00390625f;  // 1/256
        oE.y = (tE0 + tE1) * 0.015625f;                  // 4/256
        oE.z = ((tE0 + tEp) + 6.f * tE1) * 0.00390625f;
        oE.w = (tE1 + tEp) * 0.015625f;
        oO.x = ((tOm + tO1) + 6.f * tO0) * 0.015625f;    // 4/256
        oO.y = (tO0 + tO1) * 0.0625f;                    // 16/256
        oO.z = ((tO0 + tOp) + 6.f * tO1) * 0.015625f;
        oO.w = (tO1 + tOp) * 0.0625f;

        *reinterpret_cast<f32x4*>(op + (2 * r) * OW)     = oE;
        *reinterpret_cast<f32x4*>(op + (2 * r + 1) * OW) = oO;
    }
}

extern "C" void kernel_launch(void* const* d_in, const int* in_sizes, int n_in,
                              void* d_out, int out_size, void* d_ws, size_t ws_size,
                              hipStream_t stream) {
    const float* x = (const float*)d_in[0];
    float* out = (float*)d_out;

    // waves = B*C*(H/RR) = 32768 -> 2,097,152 threads -> 8192 blocks of 256
    int nblk = BB * CC * (HH / RR) * 64 / 256;  // 8192
    upfilter2d_kernel<<<dim3(nblk), dim3(256), 0, stream>>>(x, out);
}

// Round 7
// 63.865 us; speedup vs baseline: 1.3058x; 1.3058x over previous
//
#include <hip/hip_runtime.h>

// UpFilter2d: 2x zero-injection upsample + depthwise 5x5 Pascal filter, fused.
// Parity + separability: kernel = outer([1,4,6,4,1])/256. Even output
// rows/cols: taps [1,6,1]; odd: [4,4] (scales folded: 1/256, 4/256, 16/256).
//
// R6 = R5 minus the XCD swizzle (single-variable ablation; swizzle is the
// suspected -12us: streaming op, no inter-block reuse, input L3-resident --
// matches T1's null-to-negative transfer on LayerNorm-like ops).
//
// Layout: wave = RR=4 consecutive input rows of one (b,c) image.
//   - Loads RR+2=6 dense 512B float2 rows (1.5x redundancy vs 3x in R4).
//   - Vertical pass in registers, column halos via shfl (lane 0/63 edges ==
//     image edges -> zero pad).
//   - Stores 8 dense 1KiB output rows (8KiB contiguous per wave).

#define BB 8
#define CC 128
#define HH 128
#define WW 128
#define RR 4   // input rows per wave

typedef float f32x2 __attribute__((ext_vector_type(2)));
typedef float f32x4 __attribute__((ext_vector_type(4)));

__global__ __launch_bounds__(256) void upfilter2d_kernel(
    const float* __restrict__ x,
    float* __restrict__ out)
{
    int tid  = blockIdx.x * blockDim.x + threadIdx.x;

    int lane = tid & 63;
    int w    = tid >> 6;
    int rg   = w & (HH / RR - 1);   // row-group 0..31
    int bc   = w >> 5;              // 0..1023 (B*C)
    int y0   = rg * RR;

    const float* xp = x + (size_t)bc * (HH * WW) + 2 * lane;

    // rows y0-1 .. y0+RR, dense float2 per row (wave covers full 512B row)
    f32x2 v[RR + 2];
    f32x2 z = {0.f, 0.f};
    v[0] = (rg > 0) ? *reinterpret_cast<const f32x2*>(xp + (y0 - 1) * WW) : z;
#pragma unroll
    for (int r = 1; r <= RR; ++r)
        v[r] = *reinterpret_cast<const f32x2*>(xp + (y0 + r - 1) * WW);
    v[RR + 1] = (rg < HH / RR - 1)
        ? *reinterpret_cast<const f32x2*>(xp + (y0 + RR) * WW) : z;

    const int OW = 2 * WW;  // 256
    float* op = out + (size_t)bc * (2 * HH * OW) + (size_t)(2 * y0) * OW + 4 * lane;

#pragma unroll
    for (int r = 0; r < RR; ++r) {
        // vertical: even-row taps [1,6,1] on rows y-1,y,y+1; odd taps [4,4]
        float tE0 = (v[r].x + v[r + 2].x) + 6.f * v[r + 1].x;
        float tE1 = (v[r].y + v[r + 2].y) + 6.f * v[r + 1].y;
        float tO0 = v[r + 1].x + v[r + 2].x;
        float tO1 = v[r + 1].y + v[r + 2].y;

        // column halos from neighbor lanes (image edge == lane-group edge)
        float tEm = __shfl_up(tE1, 1);   if (lane == 0)  tEm = 0.f;
        float tOm = __shfl_up(tO1, 1);   if (lane == 0)  tOm = 0.f;
        float tEp = __shfl_down(tE0, 1); if (lane == 63) tEp = 0.f;
        float tOp = __shfl_down(tO0, 1); if (lane == 63) tOp = 0.f;

        // horizontal: out cols 4l..4l+3
        f32x4 oE, oO;
        oE.x = ((tEm + tE1) + 6.f * tE0) * 0.00390625f;  // 1/256
        oE.y = (tE0 + tE1) * 0.015625f;                  // 4/256
        oE.z = ((tE0 + tEp) + 6.f * tE1) * 0.00390625f;
        oE.w = (tE1 + tEp) * 0.015625f;
        oO.x = ((tOm + tO1) + 6.f * tO0) * 0.015625f;    // 4/256
        oO.y = (tO0 + tO1) * 0.0625f;                    // 16/256
        oO.z = ((tO0 + tOp) + 6.f * tO1) * 0.015625f;
        oO.w = (tO1 + tOp) * 0.0625f;

        *reinterpret_cast<f32x4*>(op + (2 * r) * OW)     = oE;
        *reinterpret_cast<f32x4*>(op + (2 * r + 1) * OW) = oO;
    }
}

extern "C" void kernel_launch(void* const* d_in, const int* in_sizes, int n_in,
                              void* d_out, int out_size, void* d_ws, size_t ws_size,
                              hipStream_t stream) {
    const float* x = (const float*)d_in[0];
    float* out = (float*)d_out;

    // waves = B*C*(H/RR) = 32768 -> 2,097,152 threads -> 8192 blocks of 256
    int nblk = BB * CC * (HH / RR) * 64 / 256;  // 8192
    upfilter2d_kernel<<<dim3(nblk), dim3(256), 0, stream>>>(x, out);
}